// Round 6
// baseline (77.211 us; speedup 1.0000x reference)
//
#include <hip/hip_runtime.h>
#include <math.h>

// Problem constants
#define Bb 4
#define Cc 64
#define Hh 64
#define Ww 64
#define Ss 20

constexpr int XC = Hh * Ww * Ss;   // 81920  : x channel stride (floats)
constexpr int XH = Ww * Ss;        // 1280   : x row stride
constexpr int XW = Ss;             // 20     : x col stride
constexpr int XB = Cc * XC;        // 5242880: x batch stride
constexpr int NSITE = Bb * Hh * Ww;    // 16384
constexpr int BKPLANE = NSITE * Ss;    // 327680 floats per partial plane

// ws layout (floats): [0,576) Weff[tap][c'], [576,585) btap[tap],
//                     [640, 640 + NPART*BKPLANE) partial Bk planes

// ---------------------------------------------------------------------------
// Kernel 1: fold the K-branch 1x1 conv into the 3x3 conv.
// Weff[tap][c'] = sum_c w2[0,64+c,tap] * w1[64+c, c']
// btap[tap]     = sum_c w2[0,64+c,tap] * b1[64+c]
// ---------------------------------------------------------------------------
__global__ void ct_fold_weights(const float* __restrict__ w1,
                                const float* __restrict__ b1,
                                const float* __restrict__ w2,
                                float* __restrict__ ws) {
    int tid = threadIdx.x;
    if (tid < 576) {
        int tap = tid >> 6, cp = tid & 63;
        float acc = 0.f;
        #pragma unroll 8
        for (int c = 0; c < 64; ++c)
            acc += w2[(64 + c) * 9 + tap] * w1[(64 + c) * 64 + cp];
        ws[tid] = acc;
    } else if (tid < 585) {
        int tap = tid - 576;
        float acc = 0.f;
        for (int c = 0; c < 64; ++c)
            acc += w2[(64 + c) * 9 + tap] * b1[64 + c];
        ws[576 + tap] = acc;
    }
}

// ---------------------------------------------------------------------------
// Kernel 2 (scatter, register-bounded): partial Bk over a channel slice.
// Block = (part, b, 4-row h-tile); threads = 64 w * 5 t4 = 320.
// DYNAMIC j-loop (#pragma unroll 1) so only ONE row's 12 float4 loads are
// live at a time (~90 VGPR, no spill). Named accumulators a0/a1/a2 rotate by
// explicit copies -> all indices compile-time (rule #20). At step j
// (x row h0-1+j): weight row 0 -> offset j, row 1 -> j-1, row 2 -> j-2;
// offset j-2 completes and is stored. Out-of-range slots hold junk that is
// never stored. Logical L2 reads: 1.5x (h-halo) instead of gather's 9x.
// ---------------------------------------------------------------------------
template<int NCP>
__global__ __launch_bounds__(320) void ct_conv_scatter(
        const float* __restrict__ x,
        const float* __restrict__ ws,
        float* __restrict__ bk) {
    constexpr int NPART = 64 / NCP;
    constexpr int HT = 4;                    // output rows per block
    constexpr int TOTAL = 4 * NPART * 16;    // grid size
    __shared__ float wsl[9 * NCP];
    __shared__ float btL[9];
    int tid = threadIdx.x;

    // XCD swizzle: h-tiles of the same (part,b) stay on one XCD.
    int g = (blockIdx.x & 7) * (TOTAL / 8) + (blockIdx.x >> 3);
    int hc = g & 15; g >>= 4;
    int b = g & 3;
    int part = g >> 2;

    if (tid < 9 * NCP)
        wsl[tid] = ws[(tid / NCP) * 64 + part * NCP + (tid % NCP)];
    if (tid < 9) btL[tid] = ws[576 + tid];
    __syncthreads();

    int w = tid / 5, t4 = tid % 5;
    int h0 = hc * HT;
    float m0 = (w == 0)  ? 0.f : 1.f;        // dw=0 reads w-1
    float m2 = (w == 63) ? 0.f : 1.f;        // dw=2 reads w+1
    int wm1 = (w == 0) ? 0 : w - 1;
    int wp1 = (w == 63) ? 63 : w + 1;
    int cw0 = wm1 * XW, cw1 = w * XW, cw2 = wp1 * XW;

    // per-weight-row bias sums (w-edge masked)
    float bw0 = btL[0] * m0 + btL[1] + btL[2] * m2;
    float bw1 = btL[3] * m0 + btL[4] + btL[5] * m2;
    float bw2 = btL[6] * m0 + btL[7] + btL[8] * m2;
    bool bias_on = (part == 0);

    const float* xbase = x + b * XB + part * NCP * XC + t4 * 4;
    float* bkp = bk + part * BKPLANE;

    // bias init for output offset o (row h0+o); junk for o >= HT (never stored)
    auto binit = [&](int o) -> float4 {
        float bs = 0.f;
        if (bias_on) {
            int ho = h0 + o;
            bs = (ho >= 1 ? bw0 : 0.f) + bw1 + (ho <= 62 ? bw2 : 0.f);
        }
        return make_float4(bs, bs, bs, bs);
    };

    float4 a0 = make_float4(0.f, 0.f, 0.f, 0.f);  // offset j-2
    float4 a1 = make_float4(0.f, 0.f, 0.f, 0.f);  // offset j-1
    float4 a2 = binit(0);                          // offset j

    #pragma unroll 1
    for (int j = 0; j < HT + 2; ++j) {
        int hr = h0 - 1 + j;
        float4 xv[NCP][3];
        if (hr >= 0 && hr < 64) {                  // wave-uniform branch
            #pragma unroll
            for (int c = 0; c < NCP; ++c) {
                const float* xr = xbase + c * XC + hr * XH;
                float4 v0 = *reinterpret_cast<const float4*>(xr + cw0);
                float4 v1 = *reinterpret_cast<const float4*>(xr + cw1);
                float4 v2 = *reinterpret_cast<const float4*>(xr + cw2);
                v0.x *= m0; v0.y *= m0; v0.z *= m0; v0.w *= m0;
                v2.x *= m2; v2.y *= m2; v2.z *= m2; v2.w *= m2;
                xv[c][0] = v0; xv[c][1] = v1; xv[c][2] = v2;
            }
        } else {
            #pragma unroll
            for (int c = 0; c < NCP; ++c)
                #pragma unroll
                for (int dw = 0; dw < 3; ++dw)
                    xv[c][dw] = make_float4(0.f, 0.f, 0.f, 0.f);
        }

        #pragma unroll
        for (int c = 0; c < NCP; ++c) {
            #pragma unroll
            for (int dw = 0; dw < 3; ++dw) {
                float w0 = wsl[(0 * 3 + dw) * NCP + c];
                float w1r = wsl[(1 * 3 + dw) * NCP + c];
                float w2r = wsl[(2 * 3 + dw) * NCP + c];
                float4 xvv = xv[c][dw];
                a2.x = fmaf(w0, xvv.x, a2.x);
                a2.y = fmaf(w0, xvv.y, a2.y);
                a2.z = fmaf(w0, xvv.z, a2.z);
                a2.w = fmaf(w0, xvv.w, a2.w);
                a1.x = fmaf(w1r, xvv.x, a1.x);
                a1.y = fmaf(w1r, xvv.y, a1.y);
                a1.z = fmaf(w1r, xvv.z, a1.z);
                a1.w = fmaf(w1r, xvv.w, a1.w);
                a0.x = fmaf(w2r, xvv.x, a0.x);
                a0.y = fmaf(w2r, xvv.y, a0.y);
                a0.z = fmaf(w2r, xvv.z, a0.z);
                a0.w = fmaf(w2r, xvv.w, a0.w);
            }
        }

        if (j >= 2) {                              // offset j-2 complete
            int ho = h0 + j - 2;
            int site = (b * 64 + ho) * 64 + w;
            *reinterpret_cast<float4*>(bkp + site * 20 + t4 * 4) = a0;
        }
        a0 = a1; a1 = a2; a2 = binit(j + 1);       // rotate (static names)
    }
}

// ---------------------------------------------------------------------------
// Kernel 2 fallback (gather) — known-good from round 3.
// ---------------------------------------------------------------------------
template<int NPART>
__global__ __launch_bounds__(320) void ct_conv_bk(
        const float* __restrict__ x,
        const float* __restrict__ ws,
        float* __restrict__ bk) {
    __shared__ float weff[576];
    __shared__ float btap[9];
    int tid = threadIdx.x;
    for (int i = tid; i < 576; i += 320) weff[i] = ws[i];
    if (tid < 9) btap[tid] = ws[576 + tid];
    __syncthreads();

    constexpr int NCP = 64 / NPART;
    constexpr int CHUNK = 256 * NPART / 8;
    int g = (blockIdx.x & 7) * CHUNK + (blockIdx.x >> 3);
    int part = g >> 8;
    int nl = g & 255;
    int b = nl >> 6, h = nl & 63;
    int w = tid / 5, t4 = tid % 5;

    float vmask[9];
    int off[9];
    #pragma unroll
    for (int dh = 0; dh < 3; ++dh) {
        int hh = h + dh - 1;
        float hv = (hh >= 0 && hh < Hh) ? 1.f : 0.f;
        int hcl = hh < 0 ? 0 : (hh > Hh - 1 ? Hh - 1 : hh);
        #pragma unroll
        for (int dw = 0; dw < 3; ++dw) {
            int wc = w + dw - 1;
            float wvd = (wc >= 0 && wc < Ww) ? 1.f : 0.f;
            int wcl = wc < 0 ? 0 : (wc > Ww - 1 ? Ww - 1 : wc);
            vmask[dh * 3 + dw] = hv * wvd;
            off[dh * 3 + dw] = hcl * XH + wcl * XW;
        }
    }

    float bsum = 0.f;
    if (part == 0) {
        #pragma unroll
        for (int tap = 0; tap < 9; ++tap) bsum += btap[tap] * vmask[tap];
    }
    float4 acc = make_float4(bsum, bsum, bsum, bsum);

    const float* xb = x + b * XB + part * NCP * XC + t4 * 4;
    #pragma unroll 2
    for (int c = 0; c < NCP; ++c) {
        const float* xc = xb + c * XC;
        #pragma unroll
        for (int tap = 0; tap < 9; ++tap) {
            float wv = weff[tap * 64 + part * NCP + c] * vmask[tap];
            const float4 xv = *reinterpret_cast<const float4*>(xc + off[tap]);
            acc.x = fmaf(wv, xv.x, acc.x);
            acc.y = fmaf(wv, xv.y, acc.y);
            acc.z = fmaf(wv, xv.z, acc.z);
            acc.w = fmaf(wv, xv.w, acc.w);
        }
    }
    int site = nl * 64 + w;
    *reinterpret_cast<float4*>(bk + part * BKPLANE + site * 20 + t4 * 4) = acc;
}

// ---------------------------------------------------------------------------
// Kernel 3: block = 8 consecutive sites, 256 threads, grid 2048.
// si = tid&7, cg = tid>>3; thread owns channels c = cg*2+k.
// Bk partial-sum over 160 threads; softmax by 8 threads; xbar -> R -> out.
// ---------------------------------------------------------------------------
template<int NPART>
__global__ __launch_bounds__(256) void ct_attn_out(
        const float* __restrict__ x,
        const float* __restrict__ w1,
        const float* __restrict__ b1,
        const float* __restrict__ bk,
        float* __restrict__ out) {
    __shared__ float w1t[64 * 65];   // w1t[cp*65 + c] = w1v[c][cp]
    __shared__ float psm[8][20];
    __shared__ float xsh[8][65];
    int tid = threadIdx.x;
    #pragma unroll
    for (int k = 0; k < 16; ++k) {
        int j = tid + k * 256;
        int r = j >> 6, q = j & 63;
        w1t[q * 65 + r] = w1[8192 + j];
    }

    int site0 = blockIdx.x * 8;

    if (tid < 160) {
        int si = tid / 20, i = tid % 20;
        float v = 0.f;
        #pragma unroll
        for (int pt = 0; pt < NPART; ++pt)
            v += bk[pt * BKPLANE + (site0 + si) * 20 + i];
        psm[si][i] = v;
    }
    __syncthreads();

    if (tid < 8) {
        float p[20];
        #pragma unroll
        for (int i = 0; i < 20; ++i) p[i] = psm[tid][i];
        float m = p[0];
        #pragma unroll
        for (int i = 1; i < 20; ++i) m = fmaxf(m, p[i]);
        float ssum = 0.f;
        #pragma unroll
        for (int i = 0; i < 20; ++i) { p[i] = __expf(p[i] - m); ssum += p[i]; }
        float inv = 1.f / ssum;
        #pragma unroll
        for (int i = 0; i < 20; ++i) psm[tid][i] = p[i] * inv;
    }
    __syncthreads();

    int si = tid & 7, cg = tid >> 3;
    int site = site0 + si;
    int b = site >> 12, hw = site & 4095;

    #pragma unroll
    for (int k = 0; k < 2; ++k) {
        int c = cg * 2 + k;
        const float* xp = x + (b * 64 + c) * XC + hw * 20;
        float xbv = 0.f;
        #pragma unroll
        for (int i = 0; i < 5; ++i) {
            float4 xv = reinterpret_cast<const float4*>(xp)[i];
            xbv = fmaf(psm[si][4 * i],     xv.x, xbv);
            xbv = fmaf(psm[si][4 * i + 1], xv.y, xbv);
            xbv = fmaf(psm[si][4 * i + 2], xv.z, xbv);
            xbv = fmaf(psm[si][4 * i + 3], xv.w, xbv);
        }
        xsh[si][c] = xbv;
    }
    __syncthreads();

    #pragma unroll
    for (int k = 0; k < 2; ++k) {
        int c = cg * 2 + k;
        float R = b1[128 + c];
        #pragma unroll 8
        for (int cp = 0; cp < 64; ++cp)
            R = fmaf(w1t[cp * 65 + c], xsh[si][cp], R);
        float* op = out + (b * 64 + c) * XC + hw * 20;
        float4 rv = make_float4(R, R, R, R);
        #pragma unroll
        for (int s4 = 0; s4 < 5; ++s4)
            reinterpret_cast<float4*>(op)[s4] = rv;
    }
}

extern "C" void kernel_launch(void* const* d_in, const int* in_sizes, int n_in,
                              void* d_out, int out_size, void* d_ws, size_t ws_size,
                              hipStream_t stream) {
    const float* x  = (const float*)d_in[0];
    const float* w1 = (const float*)d_in[1];
    const float* b1 = (const float*)d_in[2];
    const float* w2 = (const float*)d_in[3];
    // d_in[4] (b2) is mathematically dead: it cancels in the softmax over t.
    float* ws    = (float*)d_ws;
    float* bkbuf = ws + 640;
    float* out   = (float*)d_out;

    ct_fold_weights<<<1, 640, 0, stream>>>(w1, b1, w2, ws);

    size_t need16 = (size_t)(640 + 16 * BKPLANE) * sizeof(float);
    size_t need4  = (size_t)(640 + 4 * BKPLANE) * sizeof(float);
    if (ws_size >= need16) {
        // NCP=4 -> NPART=16, grid = 4*16*16 = 1024
        ct_conv_scatter<4><<<1024, 320, 0, stream>>>(x, ws, bkbuf);
        ct_attn_out<16><<<2048, 256, 0, stream>>>(x, w1, b1, bkbuf, out);
    } else if (ws_size >= need4) {
        ct_conv_bk<4><<<1024, 320, 0, stream>>>(x, ws, bkbuf);
        ct_attn_out<4><<<2048, 256, 0, stream>>>(x, w1, b1, bkbuf, out);
    } else {
        ct_conv_bk<1><<<256, 320, 0, stream>>>(x, ws, bkbuf);
        ct_attn_out<1><<<2048, 256, 0, stream>>>(x, w1, b1, bkbuf, out);
    }
}